// Round 9
// baseline (539.875 us; speedup 1.0000x reference)
//
#include <hip/hip_runtime.h>
#include <hip/hip_fp16.h>

static constexpr int NN = 50000;   // nodes
static constexpr int NE = 800000;  // edges
static constexpr int NG = 512;     // graphs

typedef unsigned int uint;
typedef unsigned short ushort;
typedef unsigned long long u64;
typedef __attribute__((ext_vector_type(8))) short short8;
typedef __attribute__((ext_vector_type(4))) float f32x4;

__device__ inline uint bfbits(float f) {
    uint u = __float_as_uint(f);
    return (u + 0x7fffu + ((u >> 16) & 1u)) >> 16;   // RNE to bf16
}
__device__ inline float bflo(uint g) { return __uint_as_float(g << 16); }
__device__ inline float bfhi(uint g) { return __uint_as_float(g & 0xffff0000u); }
__device__ inline float bf2f(ushort s) { return __uint_as_float(((uint)s) << 16); }

static constexpr int HB  = (NE + 1023) / 1024;     // 782 hist blocks (4 edges/thr)
static constexpr int WBC = 6 * 64;                 // conv wfrag blocks (K=128)
static constexpr int WBJ = 3 * 128;                // jk wfrag blocks (K=256)
static constexpr int GB  = (NN + 63) / 64;         // 782 gemm tiles
static constexpr int EB  = (NE + 255) / 256;       // fill blocks

// ------------------- prep: hist + wfrag + conv0 (fused, block-partitioned)
// [0,HB): histogram (4 edges/thread); [HB,HB+WBC): conv-W frags;
// [.. +WBJ): jk-W frags; [.. +GB): conv0 = bf16(x) @ W0 via LDS frag tile.
__global__ __launch_bounds__(256) void prep_kernel(
    const int* __restrict__ dst, const float* __restrict__ ew,
    u64* __restrict__ pk, ushort* __restrict__ rankb,
    const float* __restrict__ conv_w, ushort* __restrict__ wbc,
    const float* __restrict__ jk_w, ushort* __restrict__ wbj,
    const float* __restrict__ x, ushort* __restrict__ xwb_out)
{
    __shared__ __align__(16) ushort wf[128 * 128];   // conv0 W-frag tile (32 KB)
    int b = blockIdx.x;
    int tid = threadIdx.x;
    if (b < HB) {
        int base = b * 1024 + tid * 4;
        #pragma unroll
        for (int q = 0; q < 4; ++q) {
            int i = base + q;
            if (i < NE) {
                int d = dst[i];
                u64 v = (1ULL << 40) + (u64)(ew[i] * 16777216.0f + 0.5f);
                u64 old = atomicAdd(&pk[d], v);
                rankb[i] = (ushort)(old >> 40);
            }
        }
        return;
    }
    if (b < HB + WBC + WBJ) {                        // weight fragment conversion
        const float* s; ushort* d; int K, blk;
        if (b < HB + WBC) {
            int bb = b - HB;
            int wid = bb >> 6; blk = bb & 63;
            K = 128;
            s = conv_w + (size_t)wid * 128 * 128;
            d = wbc    + (size_t)wid * 128 * 128;
        } else {
            int bb = b - HB - WBC;
            int wid = bb >> 7; blk = bb & 127;
            K = 256;
            s = jk_w + (size_t)wid * 256 * 128;
            d = wbj  + (size_t)wid * 256 * 128;
        }
        int i = blk * 256 + tid;                     // < K*128
        int e = i & 7;
        int lane = (i >> 3) & 63;
        int rest = i >> 9;
        int nt = K >> 5;
        int t = rest % nt;
        int j = rest / nt;
        int k = t * 32 + (lane >> 4) * 8 + e;
        int col = j * 16 + (lane & 15);
        d[i] = (ushort)bfbits(s[(size_t)k * 128 + col]);
        return;
    }
    // ---- conv0: tile of 64 rows, W0 frag-converted into LDS
    int tile = b - (HB + WBC + WBJ);
    #pragma unroll
    for (int it = 0; it < 64; ++it) {
        int i = it * 256 + tid;                      // < 16384
        int e = i & 7;
        int ln = (i >> 3) & 63;
        int rest = i >> 9;                           // nt = 4
        int t = rest & 3;
        int j = rest >> 2;
        int k = t * 32 + (ln >> 4) * 8 + e;
        int col = j * 16 + (ln & 15);
        wf[i] = (ushort)bfbits(conv_w[(size_t)k * 128 + col]);
    }
    __syncthreads();
    const int wid  = tid >> 6;
    const int lane = tid & 63;
    const int row0 = tile * 64 + wid * 16;
    const int c    = lane & 15;
    const int kg   = lane >> 4;
    int arow = row0 + c;
    if (arow >= NN) arow = NN - 1;
    f32x4 acc[8];
    #pragma unroll
    for (int j = 0; j < 8; ++j) acc[j] = (f32x4)0.f;
    #pragma unroll
    for (int t = 0; t < 4; ++t) {
        const float* Ap = x + (size_t)arow * 128 + kg * 8 + t * 32;
        float4 f0 = *(const float4*)Ap;
        float4 f1 = *(const float4*)(Ap + 4);
        short8 a;
        a[0] = (short)bfbits(f0.x); a[1] = (short)bfbits(f0.y);
        a[2] = (short)bfbits(f0.z); a[3] = (short)bfbits(f0.w);
        a[4] = (short)bfbits(f1.x); a[5] = (short)bfbits(f1.y);
        a[6] = (short)bfbits(f1.z); a[7] = (short)bfbits(f1.w);
        #pragma unroll
        for (int j = 0; j < 8; ++j) {
            short8 bb = *(const short8*)&wf[((j * 4 + t) * 64 + lane) * 8];
            acc[j] = __builtin_amdgcn_mfma_f32_16x16x32_bf16(a, bb, acc[j], 0, 0, 0);
        }
    }
    #pragma unroll
    for (int r = 0; r < 4; ++r) {
        int orow = row0 + kg * 4 + r;
        if (orow >= NN) continue;
        #pragma unroll
        for (int j = 0; j < 8; ++j)
            xwb_out[(size_t)orow * 128 + j * 16 + c] = (ushort)bfbits(acc[j][r]);
    }
}

// -------------------------- scan level 1+2 fused (last-block pattern) + dinv
__global__ __launch_bounds__(256) void scan_ab_kernel(
    const u64* __restrict__ pk, int* __restrict__ bsum, float* __restrict__ dinv,
    int* __restrict__ boff, uint* __restrict__ ctr, int n, int nbs)
{
    __shared__ int wred[4];
    __shared__ int lastf;
    int tid = threadIdx.x;
    int i = blockIdx.x * 256 + tid;
    int v = 0;
    if (i < n) {
        u64 p = pk[i];
        v = (int)(p >> 40);
        float deg = (float)(p & 0xFFFFFFFFFFULL) * (1.0f / 16777216.0f) + 1.0f;
        dinv[i] = rsqrtf(deg);
    }
    int s = v;
    #pragma unroll
    for (int o = 32; o > 0; o >>= 1) s += __shfl_down(s, o, 64);
    int wid = tid >> 6;
    if ((tid & 63) == 0) wred[wid] = s;
    __syncthreads();
    if (tid == 0) {
        bsum[blockIdx.x] = wred[0] + wred[1] + wred[2] + wred[3];
        __threadfence();
        uint old = atomicAdd(ctr, 1u);
        lastf = (old == (uint)(gridDim.x - 1));
    }
    __syncthreads();
    if (!lastf) return;
    __threadfence();                               // acquire all bsum
    __shared__ int sh[256];
    int bv = (tid < nbs) ? bsum[tid] : 0;
    sh[tid] = bv;
    __syncthreads();
    #pragma unroll
    for (int o = 1; o < 256; o <<= 1) {
        int t2 = (tid >= o) ? sh[tid - o] : 0;
        __syncthreads();
        sh[tid] += t2;
        __syncthreads();
    }
    if (tid < nbs) boff[tid] = sh[tid] - bv;       // exclusive
    if (tid == 255) boff[nbs] = sh[255];           // total
}

__global__ __launch_bounds__(256) void scan_final_kernel(const u64* __restrict__ pk,
                                                         const int* __restrict__ boff,
                                                         int* __restrict__ rowptr,
                                                         int n, int nbs)
{
    __shared__ int sh[256];
    int tid = threadIdx.x;
    int i = blockIdx.x * 256 + tid;
    int v = (i < n) ? (int)(pk[i] >> 40) : 0;
    sh[tid] = v;
    __syncthreads();
    #pragma unroll
    for (int o = 1; o < 256; o <<= 1) {
        int t = (tid >= o) ? sh[tid - o] : 0;
        __syncthreads();
        sh[tid] += t;
        __syncthreads();
    }
    if (i < n) rowptr[i] = boff[blockIdx.x] + sh[tid] - v;
    if (blockIdx.x == 0 && tid == 0) rowptr[n] = boff[nbs];
}

// edge record (4B): low16 = src id, high16 = fp16(ew * dinv[src])
__global__ void fill_kernel(const int* __restrict__ src, const int* __restrict__ dst,
                            const float* __restrict__ ew, const float* __restrict__ dinv,
                            const int* __restrict__ rowptr,
                            const ushort* __restrict__ rankb,
                            uint* __restrict__ ecv, int nE)
{
    int i = blockIdx.x * blockDim.x + threadIdx.x;
    if (i < nE) {
        int s = src[i], d = dst[i];
        int pos = rowptr[d] + (int)rankb[i];
        float v = ew[i] * dinv[s];
        uint rec = (uint)s | ((uint)__half_as_ushort(__float2half_rn(v)) << 16);
        __builtin_nontemporal_store(rec, &ecv[pos]);
    }
}

// ---------------------------------------------------------- conv GEMM (MFMA)
// outb[nrows x 128] (bf16) = A[nrows x lda][0:K] (bf16) @ W-frag
__global__ __launch_bounds__(256) void conv_gemm_kernel(
    const ushort* __restrict__ Ab, int K, int lda,
    const ushort* __restrict__ Wb,
    ushort* __restrict__ outb, int nrows)
{
    const int wid  = threadIdx.x >> 6;
    const int lane = threadIdx.x & 63;
    const int row0 = blockIdx.x * 64 + wid * 16;
    const int c    = lane & 15;
    const int kg   = lane >> 4;
    int arow = row0 + c;
    if (arow >= nrows) arow = nrows - 1;
    const ushort* Aptr = Ab + (size_t)arow * lda + kg * 8;
    const int nt = K >> 5;

    f32x4 acc[8];
    #pragma unroll
    for (int j = 0; j < 8; ++j) acc[j] = (f32x4)0.f;

    for (int t = 0; t < nt; ++t) {
        short8 a = *(const short8*)(Aptr + t * 32);
        const ushort* Wp = Wb + ((size_t)t * 64 + lane) * 8;
        #pragma unroll
        for (int j = 0; j < 8; ++j) {
            short8 b = *(const short8*)(Wp + (size_t)j * nt * 512);
            acc[j] = __builtin_amdgcn_mfma_f32_16x16x32_bf16(a, b, acc[j], 0, 0, 0);
        }
    }
    #pragma unroll
    for (int r = 0; r < 4; ++r) {
        int orow = row0 + kg * 4 + r;
        if (orow >= nrows) continue;
        #pragma unroll
        for (int j = 0; j < 8; ++j)
            outb[(size_t)orow * 128 + j * 16 + c] = (ushort)bfbits(acc[j][r]);
    }
}

// -------------------------- JK gemm + pool + (chained next conv0) fused
template<bool CHAIN>
__global__ __launch_bounds__(256) void jk_fused_kernel(
    const ushort* __restrict__ xsb, const ushort* __restrict__ wbj,
    const float* __restrict__ jkb,
    const int* __restrict__ batch, float* __restrict__ z, int zoff,
    const ushort* __restrict__ wnext, ushort* __restrict__ xwb_out, int nrows)
{
    __shared__ __align__(16) ushort hl[64 * 128];
    __shared__ int sb[64];
    const int tid  = threadIdx.x;
    const int wid  = tid >> 6;
    const int lane = tid & 63;
    const int rowb = blockIdx.x * 64;
    const int row0 = rowb + wid * 16;
    const int c    = lane & 15;
    const int kg   = lane >> 4;

    if (tid < 64) {
        int rr = rowb + tid;
        sb[tid] = (rr < nrows) ? batch[rr] : -1;
    }
    int arow = row0 + c;
    if (arow >= nrows) arow = nrows - 1;
    const ushort* Aptr = xsb + (size_t)arow * 256 + kg * 8;

    f32x4 acc[8];
    #pragma unroll
    for (int j = 0; j < 8; ++j) acc[j] = (f32x4)0.f;
    for (int t = 0; t < 8; ++t) {                  // nt = 256/32
        short8 a = *(const short8*)(Aptr + t * 32);
        const ushort* Wp = wbj + ((size_t)t * 64 + lane) * 8;
        #pragma unroll
        for (int j = 0; j < 8; ++j) {
            short8 b = *(const short8*)(Wp + (size_t)j * 8 * 512);
            acc[j] = __builtin_amdgcn_mfma_f32_16x16x32_bf16(a, b, acc[j], 0, 0, 0);
        }
    }
    // bias + relu -> swizzled LDS (byte ^= (row&7)<<4)
    #pragma unroll
    for (int r = 0; r < 4; ++r) {
        int rl = wid * 16 + kg * 4 + r;
        #pragma unroll
        for (int j = 0; j < 8; ++j) {
            float v = fmaxf(acc[j][r] + jkb[j * 16 + c], 0.f);
            uint byte = ((uint)(rl * 256 + (j * 16 + c) * 2)) ^ ((uint)(rl & 7) << 4);
            *(ushort*)((char*)hl + byte) = (ushort)bfbits(v);
        }
    }
    __syncthreads();

    if (CHAIN) {                                   // h[64x128] @ Wnext (K=128)
        f32x4 ac2[8];
        #pragma unroll
        for (int j = 0; j < 8; ++j) ac2[j] = (f32x4)0.f;
        int rl2 = wid * 16 + c;
        uint rx = (uint)(rl2 & 7) << 4;
        #pragma unroll
        for (int t = 0; t < 4; ++t) {
            uint byte = ((uint)(rl2 * 256 + (kg * 8 + t * 32) * 2)) ^ rx;
            short8 a = *(const short8*)((char*)hl + byte);
            const ushort* Wp = wnext + ((size_t)t * 64 + lane) * 8;
            #pragma unroll
            for (int j = 0; j < 8; ++j) {
                short8 b = *(const short8*)(Wp + (size_t)j * 4 * 512);
                ac2[j] = __builtin_amdgcn_mfma_f32_16x16x32_bf16(a, b, ac2[j], 0, 0, 0);
            }
        }
        #pragma unroll
        for (int r = 0; r < 4; ++r) {
            int orow = row0 + kg * 4 + r;
            if (orow >= nrows) continue;
            #pragma unroll
            for (int j = 0; j < 8; ++j)
                xwb_out[(size_t)orow * 128 + j * 16 + c] = (ushort)bfbits(ac2[j][r]);
        }
    }

    // pool: threads 0..127, one col each; run-compress over 64 rows
    if (tid < 128) {
        int f = tid;
        int nend = nrows - rowb; if (nend > 64) nend = 64;
        int cur = sb[0];
        float acc2 = 0.f;
        for (int rl = 0; rl < nend; ++rl) {
            int bb = sb[rl];
            if (bb != cur) {
                atomicAdd(&z[(size_t)cur * 384 + zoff + f], acc2);
                acc2 = 0.f; cur = bb;
            }
            uint byte = ((uint)(rl * 256 + f * 2)) ^ ((uint)(rl & 7) << 4);
            acc2 += bf2f(*(const ushort*)((const char*)hl + byte));
        }
        atomicAdd(&z[(size_t)cur * 384 + zoff + f], acc2);
    }
}

// ------------------------------------------------------- sparse aggregation
// 128-thread blocks = 2 waves; one wave per node (finer retire granularity).
__global__ __launch_bounds__(128) void agg_kernel(
    const uint* __restrict__ xwb, const int* __restrict__ rowptr,
    const uint* __restrict__ ecv,
    const float* __restrict__ dinv, const float* __restrict__ bias,
    uint* __restrict__ outu, int coff, int n)
{
    int node = blockIdx.x * 2 + (threadIdx.x >> 6);
    int lane = threadIdx.x & 63;
    if (node >= n) return;
    float d = dinv[node];
    uint  g = xwb[(size_t)node * 64 + lane];
    float bx = 0.f, by = 0.f;
    int e0 = rowptr[node], e1 = rowptr[node + 1];
    int e = e0;
    for (; e + 16 <= e1; e += 16) {
        uint rec[16];
        #pragma unroll
        for (int q = 0; q < 16; ++q) rec[q] = ecv[e + q];
        uint gq[16];
        #pragma unroll
        for (int q = 0; q < 16; ++q)
            gq[q] = xwb[(size_t)(rec[q] & 0xffffu) * 64 + lane];
        #pragma unroll
        for (int q = 0; q < 16; ++q) {
            float v = __half2float(__ushort_as_half((ushort)(rec[q] >> 16)));
            bx = fmaf(v, bflo(gq[q]), bx);
            by = fmaf(v, bfhi(gq[q]), by);
        }
    }
    for (; e + 4 <= e1; e += 4) {
        uint rec[4];
        #pragma unroll
        for (int q = 0; q < 4; ++q) rec[q] = ecv[e + q];
        uint gq[4];
        #pragma unroll
        for (int q = 0; q < 4; ++q)
            gq[q] = xwb[(size_t)(rec[q] & 0xffffu) * 64 + lane];
        #pragma unroll
        for (int q = 0; q < 4; ++q) {
            float v = __half2float(__ushort_as_half((ushort)(rec[q] >> 16)));
            bx = fmaf(v, bflo(gq[q]), bx);
            by = fmaf(v, bfhi(gq[q]), by);
        }
    }
    for (; e < e1; ++e) {
        uint rec = ecv[e];
        uint gg = xwb[(size_t)(rec & 0xffffu) * 64 + lane];
        float v = __half2float(__ushort_as_half((ushort)(rec >> 16)));
        bx = fmaf(v, bflo(gg), bx);
        by = fmaf(v, bfhi(gg), by);
    }
    float sw = d * d;
    float ax = fmaf(d, bx, bflo(g) * sw);
    float ay = fmaf(d, by, bfhi(g) * sw);
    float2 b = *(const float2*)&bias[lane * 2];
    ax = fmaxf(ax + b.x, 0.f);
    ay = fmaxf(ay + b.y, 0.f);
    outu[(size_t)node * 128 + coff + lane] = bfbits(ax) | (bfbits(ay) << 16);
}

// ---------------------------------------------------------------- head
__global__ __launch_bounds__(128) void head_kernel(
    const float* __restrict__ z,
    const float* __restrict__ g,  const float* __restrict__ be,
    const float* __restrict__ mu, const float* __restrict__ var,
    const float* __restrict__ w1, const float* __restrict__ b1,
    const float* __restrict__ w2, const float* __restrict__ b2,
    float* __restrict__ out)
{
    int gi = blockIdx.x;
    int t  = threadIdx.x;
    __shared__ float zs[384];
    __shared__ float h1[128];
    __shared__ float lg[10];
    for (int i = t; i < 384; i += 128) {
        float v = z[(size_t)gi * 384 + i];
        v = (v - mu[i]) * rsqrtf(var[i] + 1e-5f) * g[i] + be[i];
        zs[i] = v;
    }
    __syncthreads();
    float acc = b1[t];
    for (int k = 0; k < 384; ++k) acc = fmaf(zs[k], w1[(size_t)k * 128 + t], acc);
    h1[t] = fmaxf(acc, 0.f);
    __syncthreads();
    if (t < 10) {
        float a2 = b2[t];
        for (int k = 0; k < 128; ++k) a2 = fmaf(h1[k], w2[(size_t)k * 10 + t], a2);
        lg[t] = a2;
    }
    __syncthreads();
    if (t == 0) {
        float m = lg[0];
        for (int i = 1; i < 10; ++i) m = fmaxf(m, lg[i]);
        float e[10], s = 0.f;
        for (int i = 0; i < 10; ++i) { e[i] = expf(lg[i] - m); s += e[i]; }
        float inv = 1.f / s;
        for (int i = 0; i < 10; ++i) out[(size_t)gi * 10 + i] = e[i] * inv;
    }
}

// ---------------------------------------------------------------- launch
extern "C" void kernel_launch(void* const* d_in, const int* in_sizes, int n_in,
                              void* d_out, int out_size, void* d_ws, size_t ws_size,
                              hipStream_t stream)
{
    const float* x      = (const float*)d_in[0];
    const float* ea     = (const float*)d_in[1];
    const float* conv_w = (const float*)d_in[2];
    const float* conv_b = (const float*)d_in[3];
    const float* jk_w   = (const float*)d_in[4];
    const float* jk_b   = (const float*)d_in[5];
    const float* bn_g   = (const float*)d_in[6];
    const float* bn_b   = (const float*)d_in[7];
    const float* bn_m   = (const float*)d_in[8];
    const float* bn_v   = (const float*)d_in[9];
    const float* w1     = (const float*)d_in[10];
    const float* b1     = (const float*)d_in[11];
    const float* w2     = (const float*)d_in[12];
    const float* b2     = (const float*)d_in[13];
    const int*   eidx   = (const int*)d_in[14];
    const int*   batch  = (const int*)d_in[15];
    const int* srcv = eidx;
    const int* dstv = eidx + NE;
    float* out = (float*)d_out;

    char* ws = (char*)d_ws;
    size_t off = 0;
    auto alloc = [&](size_t b) { size_t o = off; off += (b + 511) & ~(size_t)511; return o; };
    u64*   pk     = (u64*)  (ws + alloc((size_t)NN * 8));
    float* z      = (float*)(ws + alloc((size_t)NG * 384 * 4));
    uint*  ctr    = (uint*) (ws + alloc(512));
    size_t zero_bytes = off;
    float* dinv   = (float*)(ws + alloc((size_t)NN * 4));
    int*   rowptr = (int*)  (ws + alloc((size_t)(NN + 1) * 4));
    ushort* rankb = (ushort*)(ws + alloc((size_t)NE * 2));
    uint*  ecv    = (uint*) (ws + alloc((size_t)NE * 4));
    ushort* wbc   = (ushort*)(ws + alloc((size_t)6 * 128 * 128 * 2));
    ushort* wbj   = (ushort*)(ws + alloc((size_t)3 * 256 * 128 * 2));
    uint*  xwb    = (uint*) (ws + alloc((size_t)NN * 64 * 4));
    uint*  xsb    = (uint*) (ws + alloc((size_t)NN * 128 * 4));   // [NN][256] bf16
    int*   bsum   = (int*)  (ws + alloc((size_t)256 * 4));
    int*   boff   = (int*)  (ws + alloc((size_t)257 * 4));
    (void)ws_size; (void)in_sizes; (void)n_in; (void)out_size;

    hipMemsetAsync(d_ws, 0, zero_bytes, stream);

    const int NB = (NN + 255) / 256;
    prep_kernel<<<HB + WBC + WBJ + GB, 256, 0, stream>>>(
        dstv, ea, pk, rankb, conv_w, wbc, jk_w, wbj, x, (ushort*)xwb);
    scan_ab_kernel<<<NB, 256, 0, stream>>>(pk, bsum, dinv, boff, ctr, NN, NB);
    scan_final_kernel<<<NB, 256, 0, stream>>>(pk, boff, rowptr, NN, NB);
    fill_kernel<<<EB, 256, 0, stream>>>(srcv, dstv, ea, dinv, rowptr, rankb,
                                        ecv, NE);

    const int AB = (NN + 1) / 2;     // 25000 two-wave agg blocks

    for (int l = 0; l < 3; ++l) {
        agg_kernel<<<AB, 128, 0, stream>>>(
            xwb, rowptr, ecv, dinv, conv_b + (size_t)(l * 2 + 0) * 128,
            xsb, 0, NN);
        conv_gemm_kernel<<<GB, 256, 0, stream>>>(
            (const ushort*)xsb, 128, 256, wbc + (size_t)(l * 2 + 1) * 128 * 128,
            (ushort*)xwb, NN);
        agg_kernel<<<AB, 128, 0, stream>>>(
            xwb, rowptr, ecv, dinv, conv_b + (size_t)(l * 2 + 1) * 128,
            xsb, 64, NN);
        if (l < 2) {
            jk_fused_kernel<true><<<GB, 256, 0, stream>>>(
                (const ushort*)xsb, wbj + (size_t)l * 256 * 128,
                jk_b + (size_t)l * 128, batch, z, l * 128,
                wbc + (size_t)(l + 1) * 2 * 128 * 128, (ushort*)xwb, NN);
        } else {
            jk_fused_kernel<false><<<GB, 256, 0, stream>>>(
                (const ushort*)xsb, wbj + (size_t)l * 256 * 128,
                jk_b + (size_t)l * 128, batch, z, l * 128,
                nullptr, nullptr, NN);
        }
    }
    head_kernel<<<NG, 128, 0, stream>>>(z, bn_g, bn_b, bn_m, bn_v,
                                        w1, b1, w2, b2, out);
}

// Round 11
// 534.489 us; speedup vs baseline: 1.0101x; 1.0101x over previous
//
#include <hip/hip_runtime.h>
#include <hip/hip_fp16.h>

static constexpr int NN = 50000;   // nodes
static constexpr int NE = 800000;  // edges
static constexpr int NG = 512;     // graphs

typedef unsigned int uint;
typedef unsigned short ushort;
typedef unsigned long long u64;
typedef __attribute__((ext_vector_type(8))) short short8;
typedef __attribute__((ext_vector_type(4))) float f32x4;

__device__ inline uint bfbits(float f) {
    uint u = __float_as_uint(f);
    return (u + 0x7fffu + ((u >> 16) & 1u)) >> 16;   // RNE to bf16
}
__device__ inline float bflo(uint g) { return __uint_as_float(g << 16); }
__device__ inline float bfhi(uint g) { return __uint_as_float(g & 0xffff0000u); }
__device__ inline float bf2f(ushort s) { return __uint_as_float(((uint)s) << 16); }

static constexpr int EB  = (NE + 255) / 256;       // 3125 hist/fill blocks
static constexpr int WBC = 6 * 64;                 // conv wfrag blocks (K=128)
static constexpr int WBJ = 3 * 128;                // jk wfrag blocks (K=256)

// ------------------------------------------------ prep: hist + wfrag (fused)
// blocks [0,EB): histogram (1 edge/thread); [EB,EB+WBC): conv-W frags; rest: jk-W.
__global__ __launch_bounds__(256) void prep_kernel(
    const int* __restrict__ dst, const float* __restrict__ ew,
    u64* __restrict__ pk, ushort* __restrict__ rankb,
    const float* __restrict__ conv_w, ushort* __restrict__ wbc,
    const float* __restrict__ jk_w, ushort* __restrict__ wbj)
{
    int b = blockIdx.x;
    int tid = threadIdx.x;
    if (b < EB) {
        int i = b * 256 + tid;
        if (i < NE) {
            int d = dst[i];
            u64 v = (1ULL << 40) + (u64)(ew[i] * 16777216.0f + 0.5f);
            u64 old = atomicAdd(&pk[d], v);
            rankb[i] = (ushort)(old >> 40);
        }
        return;
    }
    const float* s; ushort* d; int K, blk;
    if (b < EB + WBC) {
        int bb = b - EB;
        int wid = bb >> 6; blk = bb & 63;
        K = 128;
        s = conv_w + (size_t)wid * 128 * 128;
        d = wbc    + (size_t)wid * 128 * 128;
    } else {
        int bb = b - EB - WBC;
        int wid = bb >> 7; blk = bb & 127;
        K = 256;
        s = jk_w + (size_t)wid * 256 * 128;
        d = wbj  + (size_t)wid * 256 * 128;
    }
    int i = blk * 256 + tid;                      // < K*128
    int e = i & 7;
    int lane = (i >> 3) & 63;
    int rest = i >> 9;
    int nt = K >> 5;
    int t = rest % nt;
    int j = rest / nt;
    int k = t * 32 + (lane >> 4) * 8 + e;
    int col = j * 16 + (lane & 15);
    d[i] = (ushort)bfbits(s[(size_t)k * 128 + col]);
}

// -------------------------- scan level 1+2 fused (last-block pattern) + dinv
__global__ __launch_bounds__(256) void scan_ab_kernel(
    const u64* __restrict__ pk, int* __restrict__ bsum, float* __restrict__ dinv,
    int* __restrict__ boff, uint* __restrict__ ctr, int n, int nbs)
{
    __shared__ int wred[4];
    __shared__ int lastf;
    int tid = threadIdx.x;
    int i = blockIdx.x * 256 + tid;
    int v = 0;
    if (i < n) {
        u64 p = pk[i];
        v = (int)(p >> 40);
        float deg = (float)(p & 0xFFFFFFFFFFULL) * (1.0f / 16777216.0f) + 1.0f;
        dinv[i] = rsqrtf(deg);
    }
    int s = v;
    #pragma unroll
    for (int o = 32; o > 0; o >>= 1) s += __shfl_down(s, o, 64);
    int wid = tid >> 6;
    if ((tid & 63) == 0) wred[wid] = s;
    __syncthreads();
    if (tid == 0) {
        bsum[blockIdx.x] = wred[0] + wred[1] + wred[2] + wred[3];
        __threadfence();
        uint old = atomicAdd(ctr, 1u);
        lastf = (old == (uint)(gridDim.x - 1));
    }
    __syncthreads();
    if (!lastf) return;
    __threadfence();                               // acquire all bsum
    __shared__ int sh[256];
    int bv = (tid < nbs) ? bsum[tid] : 0;
    sh[tid] = bv;
    __syncthreads();
    #pragma unroll
    for (int o = 1; o < 256; o <<= 1) {
        int t2 = (tid >= o) ? sh[tid - o] : 0;
        __syncthreads();
        sh[tid] += t2;
        __syncthreads();
    }
    if (tid < nbs) boff[tid] = sh[tid] - bv;       // exclusive
    if (tid == 255) boff[nbs] = sh[255];           // total
}

__global__ __launch_bounds__(256) void scan_final_kernel(const u64* __restrict__ pk,
                                                         const int* __restrict__ boff,
                                                         int* __restrict__ rowptr,
                                                         int n, int nbs)
{
    __shared__ int sh[256];
    int tid = threadIdx.x;
    int i = blockIdx.x * 256 + tid;
    int v = (i < n) ? (int)(pk[i] >> 40) : 0;
    sh[tid] = v;
    __syncthreads();
    #pragma unroll
    for (int o = 1; o < 256; o <<= 1) {
        int t = (tid >= o) ? sh[tid - o] : 0;
        __syncthreads();
        sh[tid] += t;
        __syncthreads();
    }
    if (i < n) rowptr[i] = boff[blockIdx.x] + sh[tid] - v;
    if (blockIdx.x == 0 && tid == 0) rowptr[n] = boff[nbs];
}

// edge record (4B): low16 = src id, high16 = fp16(ew * dinv[src])
__global__ void fill_kernel(const int* __restrict__ src, const int* __restrict__ dst,
                            const float* __restrict__ ew, const float* __restrict__ dinv,
                            const int* __restrict__ rowptr,
                            const ushort* __restrict__ rankb,
                            uint* __restrict__ ecv, int nE)
{
    int i = blockIdx.x * blockDim.x + threadIdx.x;
    if (i < nE) {
        int s = src[i], d = dst[i];
        int pos = rowptr[d] + (int)rankb[i];
        float v = ew[i] * dinv[s];
        uint rec = (uint)s | ((uint)__half_as_ushort(__float2half_rn(v)) << 16);
        __builtin_nontemporal_store(rec, &ecv[pos]);
    }
}

// ---------------------------------------------------------- conv GEMM (MFMA)
// outb[nrows x 128] (bf16) = A[nrows x lda][0:K] @ W-frag.  AF32: A is fp32.
template<bool AF32>
__global__ __launch_bounds__(256) void conv_gemm_kernel(
    const void* __restrict__ Aab, int K, int lda,
    const ushort* __restrict__ Wb,
    ushort* __restrict__ outb, int nrows)
{
    const int wid  = threadIdx.x >> 6;
    const int lane = threadIdx.x & 63;
    const int row0 = blockIdx.x * 64 + wid * 16;
    const int c    = lane & 15;
    const int kg   = lane >> 4;
    int arow = row0 + c;
    if (arow >= nrows) arow = nrows - 1;
    const int nt = K >> 5;

    f32x4 acc[8];
    #pragma unroll
    for (int j = 0; j < 8; ++j) acc[j] = (f32x4)0.f;

    for (int t = 0; t < nt; ++t) {
        short8 a;
        if (AF32) {
            const float* Ap = (const float*)Aab + (size_t)arow * lda + kg * 8 + t * 32;
            float4 f0 = *(const float4*)Ap;
            float4 f1 = *(const float4*)(Ap + 4);
            a[0] = (short)bfbits(f0.x); a[1] = (short)bfbits(f0.y);
            a[2] = (short)bfbits(f0.z); a[3] = (short)bfbits(f0.w);
            a[4] = (short)bfbits(f1.x); a[5] = (short)bfbits(f1.y);
            a[6] = (short)bfbits(f1.z); a[7] = (short)bfbits(f1.w);
        } else {
            a = *(const short8*)((const ushort*)Aab + (size_t)arow * lda + kg * 8 + t * 32);
        }
        const ushort* Wp = Wb + ((size_t)t * 64 + lane) * 8;
        #pragma unroll
        for (int j = 0; j < 8; ++j) {
            short8 b = *(const short8*)(Wp + (size_t)j * nt * 512);
            acc[j] = __builtin_amdgcn_mfma_f32_16x16x32_bf16(a, b, acc[j], 0, 0, 0);
        }
    }
    #pragma unroll
    for (int r = 0; r < 4; ++r) {
        int orow = row0 + kg * 4 + r;
        if (orow >= nrows) continue;
        #pragma unroll
        for (int j = 0; j < 8; ++j)
            outb[(size_t)orow * 128 + j * 16 + c] = (ushort)bfbits(acc[j][r]);
    }
}

// -------------------------- JK gemm + pool + (chained next conv0) fused
template<bool CHAIN>
__global__ __launch_bounds__(256) void jk_fused_kernel(
    const ushort* __restrict__ xsb, const ushort* __restrict__ wbj,
    const float* __restrict__ jkb,
    const int* __restrict__ batch, float* __restrict__ z, int zoff,
    const ushort* __restrict__ wnext, ushort* __restrict__ xwb_out, int nrows)
{
    __shared__ __align__(16) ushort hl[64 * 128];
    __shared__ int sb[64];
    const int tid  = threadIdx.x;
    const int wid  = tid >> 6;
    const int lane = tid & 63;
    const int rowb = blockIdx.x * 64;
    const int row0 = rowb + wid * 16;
    const int c    = lane & 15;
    const int kg   = lane >> 4;

    if (tid < 64) {
        int rr = rowb + tid;
        sb[tid] = (rr < nrows) ? batch[rr] : -1;
    }
    int arow = row0 + c;
    if (arow >= nrows) arow = nrows - 1;
    const ushort* Aptr = xsb + (size_t)arow * 256 + kg * 8;

    f32x4 acc[8];
    #pragma unroll
    for (int j = 0; j < 8; ++j) acc[j] = (f32x4)0.f;
    for (int t = 0; t < 8; ++t) {                  // nt = 256/32
        short8 a = *(const short8*)(Aptr + t * 32);
        const ushort* Wp = wbj + ((size_t)t * 64 + lane) * 8;
        #pragma unroll
        for (int j = 0; j < 8; ++j) {
            short8 b = *(const short8*)(Wp + (size_t)j * 8 * 512);
            acc[j] = __builtin_amdgcn_mfma_f32_16x16x32_bf16(a, b, acc[j], 0, 0, 0);
        }
    }
    // bias + relu -> swizzled LDS (byte ^= (row&7)<<4)
    #pragma unroll
    for (int r = 0; r < 4; ++r) {
        int rl = wid * 16 + kg * 4 + r;
        #pragma unroll
        for (int j = 0; j < 8; ++j) {
            float v = fmaxf(acc[j][r] + jkb[j * 16 + c], 0.f);
            uint byte = ((uint)(rl * 256 + (j * 16 + c) * 2)) ^ ((uint)(rl & 7) << 4);
            *(ushort*)((char*)hl + byte) = (ushort)bfbits(v);
        }
    }
    __syncthreads();

    if (CHAIN) {                                   // h[64x128] @ Wnext (K=128)
        f32x4 ac2[8];
        #pragma unroll
        for (int j = 0; j < 8; ++j) ac2[j] = (f32x4)0.f;
        int rl2 = wid * 16 + c;
        uint rx = (uint)(rl2 & 7) << 4;
        #pragma unroll
        for (int t = 0; t < 4; ++t) {
            uint byte = ((uint)(rl2 * 256 + (kg * 8 + t * 32) * 2)) ^ rx;
            short8 a = *(const short8*)((char*)hl + byte);
            const ushort* Wp = wnext + ((size_t)t * 64 + lane) * 8;
            #pragma unroll
            for (int j = 0; j < 8; ++j) {
                short8 b = *(const short8*)(Wp + (size_t)j * 4 * 512);
                ac2[j] = __builtin_amdgcn_mfma_f32_16x16x32_bf16(a, b, ac2[j], 0, 0, 0);
            }
        }
        #pragma unroll
        for (int r = 0; r < 4; ++r) {
            int orow = row0 + kg * 4 + r;
            if (orow >= nrows) continue;
            #pragma unroll
            for (int j = 0; j < 8; ++j)
                xwb_out[(size_t)orow * 128 + j * 16 + c] = (ushort)bfbits(ac2[j][r]);
        }
    }

    // pool: threads 0..127, one col each; run-compress over 64 rows
    if (tid < 128) {
        int f = tid;
        int nend = nrows - rowb; if (nend > 64) nend = 64;
        int cur = sb[0];
        float acc2 = 0.f;
        for (int rl = 0; rl < nend; ++rl) {
            int bb = sb[rl];
            if (bb != cur) {
                atomicAdd(&z[(size_t)cur * 384 + zoff + f], acc2);
                acc2 = 0.f; cur = bb;
            }
            uint byte = ((uint)(rl * 256 + f * 2)) ^ ((uint)(rl & 7) << 4);
            acc2 += bf2f(*(const ushort*)((const char*)hl + byte));
        }
        atomicAdd(&z[(size_t)cur * 384 + zoff + f], acc2);
    }
}

// ------------------------------------------------------- sparse aggregation
// one wave per node; lane holds 2 feats. 16-deep gather unroll (MLP).
__global__ __launch_bounds__(256) void agg_kernel(
    const uint* __restrict__ xwb, const int* __restrict__ rowptr,
    const uint* __restrict__ ecv,
    const float* __restrict__ dinv, const float* __restrict__ bias,
    uint* __restrict__ outu, int coff, int n)
{
    int node = (int)((blockIdx.x * (size_t)blockDim.x + threadIdx.x) >> 6);
    int lane = threadIdx.x & 63;
    if (node >= n) return;
    float d = dinv[node];
    uint  g = xwb[(size_t)node * 64 + lane];
    float bx = 0.f, by = 0.f;
    int e0 = rowptr[node], e1 = rowptr[node + 1];
    int e = e0;
    for (; e + 16 <= e1; e += 16) {
        uint rec[16];
        #pragma unroll
        for (int q = 0; q < 16; ++q) rec[q] = ecv[e + q];
        uint gq[16];
        #pragma unroll
        for (int q = 0; q < 16; ++q)
            gq[q] = xwb[(size_t)(rec[q] & 0xffffu) * 64 + lane];
        #pragma unroll
        for (int q = 0; q < 16; ++q) {
            float v = __half2float(__ushort_as_half((ushort)(rec[q] >> 16)));
            bx = fmaf(v, bflo(gq[q]), bx);
            by = fmaf(v, bfhi(gq[q]), by);
        }
    }
    for (; e + 4 <= e1; e += 4) {
        uint rec[4];
        #pragma unroll
        for (int q = 0; q < 4; ++q) rec[q] = ecv[e + q];
        uint gq[4];
        #pragma unroll
        for (int q = 0; q < 4; ++q)
            gq[q] = xwb[(size_t)(rec[q] & 0xffffu) * 64 + lane];
        #pragma unroll
        for (int q = 0; q < 4; ++q) {
            float v = __half2float(__ushort_as_half((ushort)(rec[q] >> 16)));
            bx = fmaf(v, bflo(gq[q]), bx);
            by = fmaf(v, bfhi(gq[q]), by);
        }
    }
    for (; e < e1; ++e) {
        uint rec = ecv[e];
        uint gg = xwb[(size_t)(rec & 0xffffu) * 64 + lane];
        float v = __half2float(__ushort_as_half((ushort)(rec >> 16)));
        bx = fmaf(v, bflo(gg), bx);
        by = fmaf(v, bfhi(gg), by);
    }
    float sw = d * d;
    float ax = fmaf(d, bx, bflo(g) * sw);
    float ay = fmaf(d, by, bfhi(g) * sw);
    float2 b = *(const float2*)&bias[lane * 2];
    ax = fmaxf(ax + b.x, 0.f);
    ay = fmaxf(ay + b.y, 0.f);
    outu[(size_t)node * 128 + coff + lane] = bfbits(ax) | (bfbits(ay) << 16);
}

// ---------------------------------------------------------------- head
__global__ __launch_bounds__(128) void head_kernel(
    const float* __restrict__ z,
    const float* __restrict__ g,  const float* __restrict__ be,
    const float* __restrict__ mu, const float* __restrict__ var,
    const float* __restrict__ w1, const float* __restrict__ b1,
    const float* __restrict__ w2, const float* __restrict__ b2,
    float* __restrict__ out)
{
    int gi = blockIdx.x;
    int t  = threadIdx.x;
    __shared__ float zs[384];
    __shared__ float h1[128];
    __shared__ float lg[10];
    for (int i = t; i < 384; i += 128) {
        float v = z[(size_t)gi * 384 + i];
        v = (v - mu[i]) * rsqrtf(var[i] + 1e-5f) * g[i] + be[i];
        zs[i] = v;
    }
    __syncthreads();
    float acc = b1[t];
    for (int k = 0; k < 384; ++k) acc = fmaf(zs[k], w1[(size_t)k * 128 + t], acc);
    h1[t] = fmaxf(acc, 0.f);
    __syncthreads();
    if (t < 10) {
        float a2 = b2[t];
        for (int k = 0; k < 128; ++k) a2 = fmaf(h1[k], w2[(size_t)k * 10 + t], a2);
        lg[t] = a2;
    }
    __syncthreads();
    if (t == 0) {
        float m = lg[0];
        for (int i = 1; i < 10; ++i) m = fmaxf(m, lg[i]);
        float e[10], s = 0.f;
        for (int i = 0; i < 10; ++i) { e[i] = expf(lg[i] - m); s += e[i]; }
        float inv = 1.f / s;
        for (int i = 0; i < 10; ++i) out[(size_t)gi * 10 + i] = e[i] * inv;
    }
}

// ---------------------------------------------------------------- launch
extern "C" void kernel_launch(void* const* d_in, const int* in_sizes, int n_in,
                              void* d_out, int out_size, void* d_ws, size_t ws_size,
                              hipStream_t stream)
{
    const float* x      = (const float*)d_in[0];
    const float* ea     = (const float*)d_in[1];
    const float* conv_w = (const float*)d_in[2];
    const float* conv_b = (const float*)d_in[3];
    const float* jk_w   = (const float*)d_in[4];
    const float* jk_b   = (const float*)d_in[5];
    const float* bn_g   = (const float*)d_in[6];
    const float* bn_b   = (const float*)d_in[7];
    const float* bn_m   = (const float*)d_in[8];
    const float* bn_v   = (const float*)d_in[9];
    const float* w1     = (const float*)d_in[10];
    const float* b1     = (const float*)d_in[11];
    const float* w2     = (const float*)d_in[12];
    const float* b2     = (const float*)d_in[13];
    const int*   eidx   = (const int*)d_in[14];
    const int*   batch  = (const int*)d_in[15];
    const int* srcv = eidx;
    const int* dstv = eidx + NE;
    float* out = (float*)d_out;

    char* ws = (char*)d_ws;
    size_t off = 0;
    auto alloc = [&](size_t b) { size_t o = off; off += (b + 511) & ~(size_t)511; return o; };
    u64*   pk     = (u64*)  (ws + alloc((size_t)NN * 8));
    float* z      = (float*)(ws + alloc((size_t)NG * 384 * 4));
    uint*  ctr    = (uint*) (ws + alloc(512));
    size_t zero_bytes = off;
    float* dinv   = (float*)(ws + alloc((size_t)NN * 4));
    int*   rowptr = (int*)  (ws + alloc((size_t)(NN + 1) * 4));
    ushort* rankb = (ushort*)(ws + alloc((size_t)NE * 2));
    uint*  ecv    = (uint*) (ws + alloc((size_t)NE * 4));
    ushort* wbc   = (ushort*)(ws + alloc((size_t)6 * 128 * 128 * 2));
    ushort* wbj   = (ushort*)(ws + alloc((size_t)3 * 256 * 128 * 2));
    uint*  xwb    = (uint*) (ws + alloc((size_t)NN * 64 * 4));
    uint*  xsb    = (uint*) (ws + alloc((size_t)NN * 128 * 4));   // [NN][256] bf16
    int*   bsum   = (int*)  (ws + alloc((size_t)256 * 4));
    int*   boff   = (int*)  (ws + alloc((size_t)257 * 4));
    (void)ws_size; (void)in_sizes; (void)n_in; (void)out_size;

    hipMemsetAsync(d_ws, 0, zero_bytes, stream);

    const int NB = (NN + 255) / 256;
    prep_kernel<<<EB + WBC + WBJ, 256, 0, stream>>>(dstv, ea, pk, rankb,
                                                    conv_w, wbc, jk_w, wbj);
    scan_ab_kernel<<<NB, 256, 0, stream>>>(pk, bsum, dinv, boff, ctr, NN, NB);
    scan_final_kernel<<<NB, 256, 0, stream>>>(pk, boff, rowptr, NN, NB);
    fill_kernel<<<EB, 256, 0, stream>>>(srcv, dstv, ea, dinv, rowptr, rankb,
                                        ecv, NE);

    const int GB = (NN + 63) / 64;
    const int AB = (NN * 64 + 255) / 256;

    // layer 0 conv0 from fp32 x
    conv_gemm_kernel<true><<<GB, 256, 0, stream>>>(x, 128, 128, wbc,
                                                   (ushort*)xwb, NN);
    for (int l = 0; l < 3; ++l) {
        agg_kernel<<<AB, 256, 0, stream>>>(
            xwb, rowptr, ecv, dinv, conv_b + (size_t)(l * 2 + 0) * 128,
            xsb, 0, NN);
        conv_gemm_kernel<false><<<GB, 256, 0, stream>>>(
            (const ushort*)xsb, 128, 256, wbc + (size_t)(l * 2 + 1) * 128 * 128,
            (ushort*)xwb, NN);
        agg_kernel<<<AB, 256, 0, stream>>>(
            xwb, rowptr, ecv, dinv, conv_b + (size_t)(l * 2 + 1) * 128,
            xsb, 64, NN);
        if (l < 2) {
            jk_fused_kernel<true><<<GB, 256, 0, stream>>>(
                (const ushort*)xsb, wbj + (size_t)l * 256 * 128,
                jk_b + (size_t)l * 128, batch, z, l * 128,
                wbc + (size_t)(l + 1) * 2 * 128 * 128, (ushort*)xwb, NN);
        } else {
            jk_fused_kernel<false><<<GB, 256, 0, stream>>>(
                (const ushort*)xsb, wbj + (size_t)l * 256 * 128,
                jk_b + (size_t)l * 128, batch, z, l * 128,
                nullptr, nullptr, NN);
        }
    }
    head_kernel<<<NG, 128, 0, stream>>>(z, bn_g, bn_b, bn_m, bn_v,
                                        w1, b1, w2, b2, out);
}

// Round 13
// 531.142 us; speedup vs baseline: 1.0164x; 1.0063x over previous
//
#include <hip/hip_runtime.h>
#include <hip/hip_fp16.h>

static constexpr int NN = 50000;   // nodes
static constexpr int NE = 800000;  // edges
static constexpr int NG = 512;     // graphs

typedef unsigned int uint;
typedef unsigned short ushort;
typedef unsigned long long u64;
typedef __attribute__((ext_vector_type(8))) short short8;
typedef __attribute__((ext_vector_type(4))) float f32x4;

__device__ inline uint bfbits(float f) {
    uint u = __float_as_uint(f);
    return (u + 0x7fffu + ((u >> 16) & 1u)) >> 16;   // RNE to bf16
}
__device__ inline float bflo(uint g) { return __uint_as_float(g << 16); }
__device__ inline float bfhi(uint g) { return __uint_as_float(g & 0xffff0000u); }
__device__ inline float bf2f(ushort s) { return __uint_as_float(((uint)s) << 16); }

static constexpr int EB  = (NE + 255) / 256;       // 3125 hist/fill blocks
static constexpr int WBC = 6 * 64;                 // conv wfrag blocks (K=128)
static constexpr int WBJ = 3 * 128;                // jk wfrag blocks (K=256)

// ------------------------------------------------ prep: hist + wfrag (fused)
// blocks [0,EB): histogram (1 edge/thread); [EB,EB+WBC): conv-W frags; rest: jk-W.
__global__ __launch_bounds__(256) void prep_kernel(
    const int* __restrict__ dst, const float* __restrict__ ew,
    u64* __restrict__ pk, ushort* __restrict__ rankb,
    const float* __restrict__ conv_w, ushort* __restrict__ wbc,
    const float* __restrict__ jk_w, ushort* __restrict__ wbj)
{
    int b = blockIdx.x;
    int tid = threadIdx.x;
    if (b < EB) {
        int i = b * 256 + tid;
        if (i < NE) {
            int d = dst[i];
            u64 v = (1ULL << 40) + (u64)(ew[i] * 16777216.0f + 0.5f);
            u64 old = atomicAdd(&pk[d], v);
            rankb[i] = (ushort)(old >> 40);
        }
        return;
    }
    const float* s; ushort* d; int K, blk;
    if (b < EB + WBC) {
        int bb = b - EB;
        int wid = bb >> 6; blk = bb & 63;
        K = 128;
        s = conv_w + (size_t)wid * 128 * 128;
        d = wbc    + (size_t)wid * 128 * 128;
    } else {
        int bb = b - EB - WBC;
        int wid = bb >> 7; blk = bb & 127;
        K = 256;
        s = jk_w + (size_t)wid * 256 * 128;
        d = wbj  + (size_t)wid * 256 * 128;
    }
    int i = blk * 256 + tid;                      // < K*128
    int e = i & 7;
    int lane = (i >> 3) & 63;
    int rest = i >> 9;
    int nt = K >> 5;
    int t = rest % nt;
    int j = rest / nt;
    int k = t * 32 + (lane >> 4) * 8 + e;
    int col = j * 16 + (lane & 15);
    d[i] = (ushort)bfbits(s[(size_t)k * 128 + col]);
}

// -------------------------- scan level 1+2 fused (last-block pattern) + dinv
__global__ __launch_bounds__(256) void scan_ab_kernel(
    const u64* __restrict__ pk, int* __restrict__ bsum, float* __restrict__ dinv,
    int* __restrict__ boff, uint* __restrict__ ctr, int n, int nbs)
{
    __shared__ int wred[4];
    __shared__ int lastf;
    int tid = threadIdx.x;
    int i = blockIdx.x * 256 + tid;
    int v = 0;
    if (i < n) {
        u64 p = pk[i];
        v = (int)(p >> 40);
        float deg = (float)(p & 0xFFFFFFFFFFULL) * (1.0f / 16777216.0f) + 1.0f;
        dinv[i] = rsqrtf(deg);
    }
    int s = v;
    #pragma unroll
    for (int o = 32; o > 0; o >>= 1) s += __shfl_down(s, o, 64);
    int wid = tid >> 6;
    if ((tid & 63) == 0) wred[wid] = s;
    __syncthreads();
    if (tid == 0) {
        bsum[blockIdx.x] = wred[0] + wred[1] + wred[2] + wred[3];
        __threadfence();
        uint old = atomicAdd(ctr, 1u);
        lastf = (old == (uint)(gridDim.x - 1));
    }
    __syncthreads();
    if (!lastf) return;
    __threadfence();                               // acquire all bsum
    __shared__ int sh[256];
    int bv = (tid < nbs) ? bsum[tid] : 0;
    sh[tid] = bv;
    __syncthreads();
    #pragma unroll
    for (int o = 1; o < 256; o <<= 1) {
        int t2 = (tid >= o) ? sh[tid - o] : 0;
        __syncthreads();
        sh[tid] += t2;
        __syncthreads();
    }
    if (tid < nbs) boff[tid] = sh[tid] - bv;       // exclusive
    if (tid == 255) boff[nbs] = sh[255];           // total
}

__global__ __launch_bounds__(256) void scan_final_kernel(const u64* __restrict__ pk,
                                                         const int* __restrict__ boff,
                                                         int* __restrict__ rowptr,
                                                         int n, int nbs)
{
    __shared__ int sh[256];
    int tid = threadIdx.x;
    int i = blockIdx.x * 256 + tid;
    int v = (i < n) ? (int)(pk[i] >> 40) : 0;
    sh[tid] = v;
    __syncthreads();
    #pragma unroll
    for (int o = 1; o < 256; o <<= 1) {
        int t = (tid >= o) ? sh[tid - o] : 0;
        __syncthreads();
        sh[tid] += t;
        __syncthreads();
    }
    if (i < n) rowptr[i] = boff[blockIdx.x] + sh[tid] - v;
    if (blockIdx.x == 0 && tid == 0) rowptr[n] = boff[nbs];
}

// edge record (4B): low16 = src id, high16 = fp16(ew * dinv[src])
__global__ void fill_kernel(const int* __restrict__ src, const int* __restrict__ dst,
                            const float* __restrict__ ew, const float* __restrict__ dinv,
                            const int* __restrict__ rowptr,
                            const ushort* __restrict__ rankb,
                            uint* __restrict__ ecv, int nE)
{
    int i = blockIdx.x * blockDim.x + threadIdx.x;
    if (i < nE) {
        int s = src[i], d = dst[i];
        int pos = rowptr[d] + (int)rankb[i];
        float v = ew[i] * dinv[s];
        ecv[pos] = (uint)s | ((uint)__half_as_ushort(__float2half_rn(v)) << 16);
    }
}

// ---------------------------------------------------------- conv GEMM (MFMA)
// outb[nrows x 128] (bf16) = A[nrows x lda][0:K] @ W-frag.  AF32: A is fp32.
template<bool AF32>
__global__ __launch_bounds__(256) void conv_gemm_kernel(
    const void* __restrict__ Aab, int K, int lda,
    const ushort* __restrict__ Wb,
    ushort* __restrict__ outb, int nrows)
{
    const int wid  = threadIdx.x >> 6;
    const int lane = threadIdx.x & 63;
    const int row0 = blockIdx.x * 64 + wid * 16;
    const int c    = lane & 15;
    const int kg   = lane >> 4;
    int arow = row0 + c;
    if (arow >= nrows) arow = nrows - 1;
    const int nt = K >> 5;

    f32x4 acc[8];
    #pragma unroll
    for (int j = 0; j < 8; ++j) acc[j] = (f32x4)0.f;

    for (int t = 0; t < nt; ++t) {
        short8 a;
        if (AF32) {
            const float* Ap = (const float*)Aab + (size_t)arow * lda + kg * 8 + t * 32;
            float4 f0 = *(const float4*)Ap;
            float4 f1 = *(const float4*)(Ap + 4);
            a[0] = (short)bfbits(f0.x); a[1] = (short)bfbits(f0.y);
            a[2] = (short)bfbits(f0.z); a[3] = (short)bfbits(f0.w);
            a[4] = (short)bfbits(f1.x); a[5] = (short)bfbits(f1.y);
            a[6] = (short)bfbits(f1.z); a[7] = (short)bfbits(f1.w);
        } else {
            a = *(const short8*)((const ushort*)Aab + (size_t)arow * lda + kg * 8 + t * 32);
        }
        const ushort* Wp = Wb + ((size_t)t * 64 + lane) * 8;
        #pragma unroll
        for (int j = 0; j < 8; ++j) {
            short8 b = *(const short8*)(Wp + (size_t)j * nt * 512);
            acc[j] = __builtin_amdgcn_mfma_f32_16x16x32_bf16(a, b, acc[j], 0, 0, 0);
        }
    }
    #pragma unroll
    for (int r = 0; r < 4; ++r) {
        int orow = row0 + kg * 4 + r;
        if (orow >= nrows) continue;
        #pragma unroll
        for (int j = 0; j < 8; ++j)
            outb[(size_t)orow * 128 + j * 16 + c] = (ushort)bfbits(acc[j][r]);
    }
}

// -------------------------- JK gemm + pool + (chained next conv0) fused
template<bool CHAIN>
__global__ __launch_bounds__(256) void jk_fused_kernel(
    const ushort* __restrict__ xsb, const ushort* __restrict__ wbj,
    const float* __restrict__ jkb,
    const int* __restrict__ batch, float* __restrict__ z, int zoff,
    const ushort* __restrict__ wnext, ushort* __restrict__ xwb_out, int nrows)
{
    __shared__ __align__(16) ushort hl[64 * 128];
    __shared__ int sb[64];
    const int tid  = threadIdx.x;
    const int wid  = tid >> 6;
    const int lane = tid & 63;
    const int rowb = blockIdx.x * 64;
    const int row0 = rowb + wid * 16;
    const int c    = lane & 15;
    const int kg   = lane >> 4;

    if (tid < 64) {
        int rr = rowb + tid;
        sb[tid] = (rr < nrows) ? batch[rr] : -1;
    }
    int arow = row0 + c;
    if (arow >= nrows) arow = nrows - 1;
    const ushort* Aptr = xsb + (size_t)arow * 256 + kg * 8;

    f32x4 acc[8];
    #pragma unroll
    for (int j = 0; j < 8; ++j) acc[j] = (f32x4)0.f;
    for (int t = 0; t < 8; ++t) {                  // nt = 256/32
        short8 a = *(const short8*)(Aptr + t * 32);
        const ushort* Wp = wbj + ((size_t)t * 64 + lane) * 8;
        #pragma unroll
        for (int j = 0; j < 8; ++j) {
            short8 b = *(const short8*)(Wp + (size_t)j * 8 * 512);
            acc[j] = __builtin_amdgcn_mfma_f32_16x16x32_bf16(a, b, acc[j], 0, 0, 0);
        }
    }
    // bias + relu -> swizzled LDS (byte ^= (row&7)<<4)
    #pragma unroll
    for (int r = 0; r < 4; ++r) {
        int rl = wid * 16 + kg * 4 + r;
        #pragma unroll
        for (int j = 0; j < 8; ++j) {
            float v = fmaxf(acc[j][r] + jkb[j * 16 + c], 0.f);
            uint byte = ((uint)(rl * 256 + (j * 16 + c) * 2)) ^ ((uint)(rl & 7) << 4);
            *(ushort*)((char*)hl + byte) = (ushort)bfbits(v);
        }
    }
    __syncthreads();

    if (CHAIN) {                                   // h[64x128] @ Wnext (K=128)
        f32x4 ac2[8];
        #pragma unroll
        for (int j = 0; j < 8; ++j) ac2[j] = (f32x4)0.f;
        int rl2 = wid * 16 + c;
        uint rx = (uint)(rl2 & 7) << 4;
        #pragma unroll
        for (int t = 0; t < 4; ++t) {
            uint byte = ((uint)(rl2 * 256 + (kg * 8 + t * 32) * 2)) ^ rx;
            short8 a = *(const short8*)((char*)hl + byte);
            const ushort* Wp = wnext + ((size_t)t * 64 + lane) * 8;
            #pragma unroll
            for (int j = 0; j < 8; ++j) {
                short8 b = *(const short8*)(Wp + (size_t)j * 4 * 512);
                ac2[j] = __builtin_amdgcn_mfma_f32_16x16x32_bf16(a, b, ac2[j], 0, 0, 0);
            }
        }
        #pragma unroll
        for (int r = 0; r < 4; ++r) {
            int orow = row0 + kg * 4 + r;
            if (orow >= nrows) continue;
            #pragma unroll
            for (int j = 0; j < 8; ++j)
                xwb_out[(size_t)orow * 128 + j * 16 + c] = (ushort)bfbits(ac2[j][r]);
        }
    }

    // pool: threads 0..127, one col each; run-compress over 64 rows
    if (tid < 128) {
        int f = tid;
        int nend = nrows - rowb; if (nend > 64) nend = 64;
        int cur = sb[0];
        float acc2 = 0.f;
        for (int rl = 0; rl < nend; ++rl) {
            int bb = sb[rl];
            if (bb != cur) {
                atomicAdd(&z[(size_t)cur * 384 + zoff + f], acc2);
                acc2 = 0.f; cur = bb;
            }
            uint byte = ((uint)(rl * 256 + f * 2)) ^ ((uint)(rl & 7) << 4);
            acc2 += bf2f(*(const ushort*)((const char*)hl + byte));
        }
        atomicAdd(&z[(size_t)cur * 384 + zoff + f], acc2);
    }
}

// ------------------------------------------------------- sparse aggregation
// one wave per node. Uniform masked 16-deep gather loop: every iteration
// issues 16 gathers (masked slots clamp to e1-1, weight 0 -> bit-identical),
// so all waves run at MLP=16 incl. sub-16-degree nodes and tails.
__global__ __launch_bounds__(256) void agg_kernel(
    const uint* __restrict__ xwb, const int* __restrict__ rowptr,
    const uint* __restrict__ ecv,
    const float* __restrict__ dinv, const float* __restrict__ bias,
    uint* __restrict__ outu, int coff, int n)
{
    int node = (int)((blockIdx.x * (size_t)blockDim.x + threadIdx.x) >> 6);
    int lane = threadIdx.x & 63;
    if (node >= n) return;
    float d = dinv[node];
    uint  g = xwb[(size_t)node * 64 + lane];
    float bx = 0.f, by = 0.f;
    int e0 = rowptr[node], e1 = rowptr[node + 1];
    for (int e = e0; e < e1; e += 16) {
        uint rec[16];
        #pragma unroll
        for (int q = 0; q < 16; ++q) {
            int ee = e + q;
            rec[q] = ecv[ee < e1 ? ee : e1 - 1];
        }
        uint gq[16];
        #pragma unroll
        for (int q = 0; q < 16; ++q)
            gq[q] = xwb[(size_t)(rec[q] & 0xffffu) * 64 + lane];
        #pragma unroll
        for (int q = 0; q < 16; ++q) {
            float v = (e + q < e1)
                    ? __half2float(__ushort_as_half((ushort)(rec[q] >> 16)))
                    : 0.f;
            bx = fmaf(v, bflo(gq[q]), bx);
            by = fmaf(v, bfhi(gq[q]), by);
        }
    }
    float sw = d * d;
    float ax = fmaf(d, bx, bflo(g) * sw);
    float ay = fmaf(d, by, bfhi(g) * sw);
    float2 b = *(const float2*)&bias[lane * 2];
    ax = fmaxf(ax + b.x, 0.f);
    ay = fmaxf(ay + b.y, 0.f);
    outu[(size_t)node * 128 + coff + lane] = bfbits(ax) | (bfbits(ay) << 16);
}

// ---------------------------------------------------------------- head
__global__ __launch_bounds__(128) void head_kernel(
    const float* __restrict__ z,
    const float* __restrict__ g,  const float* __restrict__ be,
    const float* __restrict__ mu, const float* __restrict__ var,
    const float* __restrict__ w1, const float* __restrict__ b1,
    const float* __restrict__ w2, const float* __restrict__ b2,
    float* __restrict__ out)
{
    int gi = blockIdx.x;
    int t  = threadIdx.x;
    __shared__ float zs[384];
    __shared__ float h1[128];
    __shared__ float lg[10];
    for (int i = t; i < 384; i += 128) {
        float v = z[(size_t)gi * 384 + i];
        v = (v - mu[i]) * rsqrtf(var[i] + 1e-5f) * g[i] + be[i];
        zs[i] = v;
    }
    __syncthreads();
    float acc = b1[t];
    for (int k = 0; k < 384; ++k) acc = fmaf(zs[k], w1[(size_t)k * 128 + t], acc);
    h1[t] = fmaxf(acc, 0.f);
    __syncthreads();
    if (t < 10) {
        float a2 = b2[t];
        for (int k = 0; k < 128; ++k) a2 = fmaf(h1[k], w2[(size_t)k * 10 + t], a2);
        lg[t] = a2;
    }
    __syncthreads();
    if (t == 0) {
        float m = lg[0];
        for (int i = 1; i < 10; ++i) m = fmaxf(m, lg[i]);
        float e[10], s = 0.f;
        for (int i = 0; i < 10; ++i) { e[i] = expf(lg[i] - m); s += e[i]; }
        float inv = 1.f / s;
        for (int i = 0; i < 10; ++i) out[(size_t)gi * 10 + i] = e[i] * inv;
    }
}

// ---------------------------------------------------------------- launch
extern "C" void kernel_launch(void* const* d_in, const int* in_sizes, int n_in,
                              void* d_out, int out_size, void* d_ws, size_t ws_size,
                              hipStream_t stream)
{
    const float* x      = (const float*)d_in[0];
    const float* ea     = (const float*)d_in[1];
    const float* conv_w = (const float*)d_in[2];
    const float* conv_b = (const float*)d_in[3];
    const float* jk_w   = (const float*)d_in[4];
    const float* jk_b   = (const float*)d_in[5];
    const float* bn_g   = (const float*)d_in[6];
    const float* bn_b   = (const float*)d_in[7];
    const float* bn_m   = (const float*)d_in[8];
    const float* bn_v   = (const float*)d_in[9];
    const float* w1     = (const float*)d_in[10];
    const float* b1     = (const float*)d_in[11];
    const float* w2     = (const float*)d_in[12];
    const float* b2     = (const float*)d_in[13];
    const int*   eidx   = (const int*)d_in[14];
    const int*   batch  = (const int*)d_in[15];
    const int* srcv = eidx;
    const int* dstv = eidx + NE;
    float* out = (float*)d_out;

    char* ws = (char*)d_ws;
    size_t off = 0;
    auto alloc = [&](size_t b) { size_t o = off; off += (b + 511) & ~(size_t)511; return o; };
    u64*   pk     = (u64*)  (ws + alloc((size_t)NN * 8));
    float* z      = (float*)(ws + alloc((size_t)NG * 384 * 4));
    uint*  ctr    = (uint*) (ws + alloc(512));
    size_t zero_bytes = off;
    float* dinv   = (float*)(ws + alloc((size_t)NN * 4));
    int*   rowptr = (int*)  (ws + alloc((size_t)(NN + 1) * 4));
    ushort* rankb = (ushort*)(ws + alloc((size_t)NE * 2));
    uint*  ecv    = (uint*) (ws + alloc((size_t)NE * 4));
    ushort* wbc   = (ushort*)(ws + alloc((size_t)6 * 128 * 128 * 2));
    ushort* wbj   = (ushort*)(ws + alloc((size_t)3 * 256 * 128 * 2));
    uint*  xwb    = (uint*) (ws + alloc((size_t)NN * 64 * 4));
    uint*  xsb    = (uint*) (ws + alloc((size_t)NN * 128 * 4));   // [NN][256] bf16
    int*   bsum   = (int*)  (ws + alloc((size_t)256 * 4));
    int*   boff   = (int*)  (ws + alloc((size_t)257 * 4));
    (void)ws_size; (void)in_sizes; (void)n_in; (void)out_size;

    hipMemsetAsync(d_ws, 0, zero_bytes, stream);

    const int NB = (NN + 255) / 256;
    prep_kernel<<<EB + WBC + WBJ, 256, 0, stream>>>(dstv, ea, pk, rankb,
                                                    conv_w, wbc, jk_w, wbj);
    scan_ab_kernel<<<NB, 256, 0, stream>>>(pk, bsum, dinv, boff, ctr, NN, NB);
    scan_final_kernel<<<NB, 256, 0, stream>>>(pk, boff, rowptr, NN, NB);
    fill_kernel<<<EB, 256, 0, stream>>>(srcv, dstv, ea, dinv, rowptr, rankb,
                                        ecv, NE);

    const int GB = (NN + 63) / 64;
    const int AB = (NN * 64 + 255) / 256;

    // layer 0 conv0 from fp32 x
    conv_gemm_kernel<true><<<GB, 256, 0, stream>>>(x, 128, 128, wbc,
                                                   (ushort*)xwb, NN);
    for (int l = 0; l < 3; ++l) {
        agg_kernel<<<AB, 256, 0, stream>>>(
            xwb, rowptr, ecv, dinv, conv_b + (size_t)(l * 2 + 0) * 128,
            xsb, 0, NN);
        conv_gemm_kernel<false><<<GB, 256, 0, stream>>>(
            (const ushort*)xsb, 128, 256, wbc + (size_t)(l * 2 + 1) * 128 * 128,
            (ushort*)xwb, NN);
        agg_kernel<<<AB, 256, 0, stream>>>(
            xwb, rowptr, ecv, dinv, conv_b + (size_t)(l * 2 + 1) * 128,
            xsb, 64, NN);
        if (l < 2) {
            jk_fused_kernel<true><<<GB, 256, 0, stream>>>(
                (const ushort*)xsb, wbj + (size_t)l * 256 * 128,
                jk_b + (size_t)l * 128, batch, z, l * 128,
                wbc + (size_t)(l + 1) * 2 * 128 * 128, (ushort*)xwb, NN);
        } else {
            jk_fused_kernel<false><<<GB, 256, 0, stream>>>(
                (const ushort*)xsb, wbj + (size_t)l * 256 * 128,
                jk_b + (size_t)l * 128, batch, z, l * 128,
                nullptr, nullptr, NN);
        }
    }
    head_kernel<<<NG, 128, 0, stream>>>(z, bn_g, bn_b, bn_m, bn_v,
                                        w1, b1, w2, b2, out);
}

// Round 14
// 514.809 us; speedup vs baseline: 1.0487x; 1.0317x over previous
//
#include <hip/hip_runtime.h>
#include <hip/hip_fp16.h>

static constexpr int NN = 50000;   // nodes
static constexpr int NE = 800000;  // edges
static constexpr int NG = 512;     // graphs

typedef unsigned int uint;
typedef unsigned short ushort;
typedef unsigned long long u64;
typedef __attribute__((ext_vector_type(8))) short short8;
typedef __attribute__((ext_vector_type(4))) float f32x4;

__device__ inline uint bfbits(float f) {
    uint u = __float_as_uint(f);
    return (u + 0x7fffu + ((u >> 16) & 1u)) >> 16;   // RNE to bf16
}
__device__ inline float bflo(uint g) { return __uint_as_float(g << 16); }
__device__ inline float bfhi(uint g) { return __uint_as_float(g & 0xffff0000u); }
__device__ inline float bf2f(ushort s) { return __uint_as_float(((uint)s) << 16); }

static constexpr int EB  = (NE + 255) / 256;       // 3125 hist/fill blocks
static constexpr int WBC = 6 * 64;                 // conv wfrag blocks (K=128)
static constexpr int WBJ = 3 * 128;                // jk wfrag blocks (K=256)
static constexpr int GB  = (NN + 63) / 64;         // 782 gemm tiles

// ------------------------------------------------ prep: hist + wfrag (fused)
// blocks [0,EB): histogram (1 edge/thread); [EB,EB+WBC): conv-W frags; rest: jk-W.
__global__ __launch_bounds__(256) void prep_kernel(
    const int* __restrict__ dst, const float* __restrict__ ew,
    u64* __restrict__ pk, ushort* __restrict__ rankb,
    const float* __restrict__ conv_w, ushort* __restrict__ wbc,
    const float* __restrict__ jk_w, ushort* __restrict__ wbj)
{
    int b = blockIdx.x;
    int tid = threadIdx.x;
    if (b < EB) {
        int i = b * 256 + tid;
        if (i < NE) {
            int d = dst[i];
            u64 v = (1ULL << 40) + (u64)(ew[i] * 16777216.0f + 0.5f);
            u64 old = atomicAdd(&pk[d], v);
            rankb[i] = (ushort)(old >> 40);
        }
        return;
    }
    const float* s; ushort* d; int K, blk;
    if (b < EB + WBC) {
        int bb = b - EB;
        int wid = bb >> 6; blk = bb & 63;
        K = 128;
        s = conv_w + (size_t)wid * 128 * 128;
        d = wbc    + (size_t)wid * 128 * 128;
    } else {
        int bb = b - EB - WBC;
        int wid = bb >> 7; blk = bb & 127;
        K = 256;
        s = jk_w + (size_t)wid * 256 * 128;
        d = wbj  + (size_t)wid * 256 * 128;
    }
    int i = blk * 256 + tid;                      // < K*128
    int e = i & 7;
    int lane = (i >> 3) & 63;
    int rest = i >> 9;
    int nt = K >> 5;
    int t = rest % nt;
    int j = rest / nt;
    int k = t * 32 + (lane >> 4) * 8 + e;
    int col = j * 16 + (lane & 15);
    d[i] = (ushort)bfbits(s[(size_t)k * 128 + col]);
}

// -------------------------- scan level 1+2 fused (last-block pattern) + dinv
__global__ __launch_bounds__(256) void scan_ab_kernel(
    const u64* __restrict__ pk, int* __restrict__ bsum, float* __restrict__ dinv,
    int* __restrict__ boff, uint* __restrict__ ctr, int n, int nbs)
{
    __shared__ int wred[4];
    __shared__ int lastf;
    int tid = threadIdx.x;
    int i = blockIdx.x * 256 + tid;
    int v = 0;
    if (i < n) {
        u64 p = pk[i];
        v = (int)(p >> 40);
        float deg = (float)(p & 0xFFFFFFFFFFULL) * (1.0f / 16777216.0f) + 1.0f;
        dinv[i] = rsqrtf(deg);
    }
    int s = v;
    #pragma unroll
    for (int o = 32; o > 0; o >>= 1) s += __shfl_down(s, o, 64);
    int wid = tid >> 6;
    if ((tid & 63) == 0) wred[wid] = s;
    __syncthreads();
    if (tid == 0) {
        bsum[blockIdx.x] = wred[0] + wred[1] + wred[2] + wred[3];
        __threadfence();
        uint old = atomicAdd(ctr, 1u);
        lastf = (old == (uint)(gridDim.x - 1));
    }
    __syncthreads();
    if (!lastf) return;
    __threadfence();                               // acquire all bsum
    __shared__ int sh[256];
    int bv = (tid < nbs) ? bsum[tid] : 0;
    sh[tid] = bv;
    __syncthreads();
    #pragma unroll
    for (int o = 1; o < 256; o <<= 1) {
        int t2 = (tid >= o) ? sh[tid - o] : 0;
        __syncthreads();
        sh[tid] += t2;
        __syncthreads();
    }
    if (tid < nbs) boff[tid] = sh[tid] - bv;       // exclusive
    if (tid == 255) boff[nbs] = sh[255];           // total
}

__global__ __launch_bounds__(256) void scan_final_kernel(const u64* __restrict__ pk,
                                                         const int* __restrict__ boff,
                                                         int* __restrict__ rowptr,
                                                         int n, int nbs)
{
    __shared__ int sh[256];
    int tid = threadIdx.x;
    int i = blockIdx.x * 256 + tid;
    int v = (i < n) ? (int)(pk[i] >> 40) : 0;
    sh[tid] = v;
    __syncthreads();
    #pragma unroll
    for (int o = 1; o < 256; o <<= 1) {
        int t = (tid >= o) ? sh[tid - o] : 0;
        __syncthreads();
        sh[tid] += t;
        __syncthreads();
    }
    if (i < n) rowptr[i] = boff[blockIdx.x] + sh[tid] - v;
    if (blockIdx.x == 0 && tid == 0) rowptr[n] = boff[nbs];
}

// --------------------- fill + conv0 (fused, block-partitioned, independent)
// [0,EB): edge record scatter; [EB,EB+GB): conv0 = bf16(x) @ W0-frag -> xwb.
__global__ __launch_bounds__(256) void fillconv_kernel(
    const int* __restrict__ src, const int* __restrict__ dst,
    const float* __restrict__ ew, const float* __restrict__ dinv,
    const int* __restrict__ rowptr, const ushort* __restrict__ rankb,
    uint* __restrict__ ecv,
    const float* __restrict__ x, const ushort* __restrict__ wbc,
    ushort* __restrict__ xwb_out)
{
    int b = blockIdx.x;
    if (b < EB) {                                  // ---- fill partition
        int i = b * 256 + threadIdx.x;
        if (i < NE) {
            int s = src[i], d = dst[i];
            int pos = rowptr[d] + (int)rankb[i];
            float v = ew[i] * dinv[s];
            ecv[pos] = (uint)s | ((uint)__half_as_ushort(__float2half_rn(v)) << 16);
        }
        return;
    }
    // ---- conv0 partition: tile of 64 rows, A = fp32 x, K = 128
    const int tile = b - EB;
    const int wid  = threadIdx.x >> 6;
    const int lane = threadIdx.x & 63;
    const int row0 = tile * 64 + wid * 16;
    const int c    = lane & 15;
    const int kg   = lane >> 4;
    int arow = row0 + c;
    if (arow >= NN) arow = NN - 1;

    f32x4 acc[8];
    #pragma unroll
    for (int j = 0; j < 8; ++j) acc[j] = (f32x4)0.f;
    #pragma unroll
    for (int t = 0; t < 4; ++t) {                  // nt = 128/32
        const float* Ap = x + (size_t)arow * 128 + kg * 8 + t * 32;
        float4 f0 = *(const float4*)Ap;
        float4 f1 = *(const float4*)(Ap + 4);
        short8 a;
        a[0] = (short)bfbits(f0.x); a[1] = (short)bfbits(f0.y);
        a[2] = (short)bfbits(f0.z); a[3] = (short)bfbits(f0.w);
        a[4] = (short)bfbits(f1.x); a[5] = (short)bfbits(f1.y);
        a[6] = (short)bfbits(f1.z); a[7] = (short)bfbits(f1.w);
        const ushort* Wp = wbc + ((size_t)t * 64 + lane) * 8;
        #pragma unroll
        for (int j = 0; j < 8; ++j) {
            short8 bb = *(const short8*)(Wp + (size_t)j * 4 * 512);
            acc[j] = __builtin_amdgcn_mfma_f32_16x16x32_bf16(a, bb, acc[j], 0, 0, 0);
        }
    }
    #pragma unroll
    for (int r = 0; r < 4; ++r) {
        int orow = row0 + kg * 4 + r;
        if (orow >= NN) continue;
        #pragma unroll
        for (int j = 0; j < 8; ++j)
            xwb_out[(size_t)orow * 128 + j * 16 + c] = (ushort)bfbits(acc[j][r]);
    }
}

// ---------------------------------------------------------- conv GEMM (MFMA)
// outb[nrows x 128] (bf16) = A[nrows x lda][0:K] (bf16) @ W-frag
__global__ __launch_bounds__(256) void conv_gemm_kernel(
    const ushort* __restrict__ Ab, int K, int lda,
    const ushort* __restrict__ Wb,
    ushort* __restrict__ outb, int nrows)
{
    const int wid  = threadIdx.x >> 6;
    const int lane = threadIdx.x & 63;
    const int row0 = blockIdx.x * 64 + wid * 16;
    const int c    = lane & 15;
    const int kg   = lane >> 4;
    int arow = row0 + c;
    if (arow >= nrows) arow = nrows - 1;
    const ushort* Aptr = Ab + (size_t)arow * lda + kg * 8;
    const int nt = K >> 5;

    f32x4 acc[8];
    #pragma unroll
    for (int j = 0; j < 8; ++j) acc[j] = (f32x4)0.f;

    for (int t = 0; t < nt; ++t) {
        short8 a = *(const short8*)(Aptr + t * 32);
        const ushort* Wp = Wb + ((size_t)t * 64 + lane) * 8;
        #pragma unroll
        for (int j = 0; j < 8; ++j) {
            short8 b = *(const short8*)(Wp + (size_t)j * nt * 512);
            acc[j] = __builtin_amdgcn_mfma_f32_16x16x32_bf16(a, b, acc[j], 0, 0, 0);
        }
    }
    #pragma unroll
    for (int r = 0; r < 4; ++r) {
        int orow = row0 + kg * 4 + r;
        if (orow >= nrows) continue;
        #pragma unroll
        for (int j = 0; j < 8; ++j)
            outb[(size_t)orow * 128 + j * 16 + c] = (ushort)bfbits(acc[j][r]);
    }
}

// -------------------------- JK gemm + pool + (chained next conv0) fused
template<bool CHAIN>
__global__ __launch_bounds__(256) void jk_fused_kernel(
    const ushort* __restrict__ xsb, const ushort* __restrict__ wbj,
    const float* __restrict__ jkb,
    const int* __restrict__ batch, float* __restrict__ z, int zoff,
    const ushort* __restrict__ wnext, ushort* __restrict__ xwb_out, int nrows)
{
    __shared__ __align__(16) ushort hl[64 * 128];
    __shared__ int sb[64];
    const int tid  = threadIdx.x;
    const int wid  = tid >> 6;
    const int lane = tid & 63;
    const int rowb = blockIdx.x * 64;
    const int row0 = rowb + wid * 16;
    const int c    = lane & 15;
    const int kg   = lane >> 4;

    if (tid < 64) {
        int rr = rowb + tid;
        sb[tid] = (rr < nrows) ? batch[rr] : -1;
    }
    int arow = row0 + c;
    if (arow >= nrows) arow = nrows - 1;
    const ushort* Aptr = xsb + (size_t)arow * 256 + kg * 8;

    f32x4 acc[8];
    #pragma unroll
    for (int j = 0; j < 8; ++j) acc[j] = (f32x4)0.f;
    for (int t = 0; t < 8; ++t) {                  // nt = 256/32
        short8 a = *(const short8*)(Aptr + t * 32);
        const ushort* Wp = wbj + ((size_t)t * 64 + lane) * 8;
        #pragma unroll
        for (int j = 0; j < 8; ++j) {
            short8 b = *(const short8*)(Wp + (size_t)j * 8 * 512);
            acc[j] = __builtin_amdgcn_mfma_f32_16x16x32_bf16(a, b, acc[j], 0, 0, 0);
        }
    }
    // bias + relu -> swizzled LDS (byte ^= (row&7)<<4)
    #pragma unroll
    for (int r = 0; r < 4; ++r) {
        int rl = wid * 16 + kg * 4 + r;
        #pragma unroll
        for (int j = 0; j < 8; ++j) {
            float v = fmaxf(acc[j][r] + jkb[j * 16 + c], 0.f);
            uint byte = ((uint)(rl * 256 + (j * 16 + c) * 2)) ^ ((uint)(rl & 7) << 4);
            *(ushort*)((char*)hl + byte) = (ushort)bfbits(v);
        }
    }
    __syncthreads();

    if (CHAIN) {                                   // h[64x128] @ Wnext (K=128)
        f32x4 ac2[8];
        #pragma unroll
        for (int j = 0; j < 8; ++j) ac2[j] = (f32x4)0.f;
        int rl2 = wid * 16 + c;
        uint rx = (uint)(rl2 & 7) << 4;
        #pragma unroll
        for (int t = 0; t < 4; ++t) {
            uint byte = ((uint)(rl2 * 256 + (kg * 8 + t * 32) * 2)) ^ rx;
            short8 a = *(const short8*)((char*)hl + byte);
            const ushort* Wp = wnext + ((size_t)t * 64 + lane) * 8;
            #pragma unroll
            for (int j = 0; j < 8; ++j) {
                short8 b = *(const short8*)(Wp + (size_t)j * 4 * 512);
                ac2[j] = __builtin_amdgcn_mfma_f32_16x16x32_bf16(a, b, ac2[j], 0, 0, 0);
            }
        }
        #pragma unroll
        for (int r = 0; r < 4; ++r) {
            int orow = row0 + kg * 4 + r;
            if (orow >= nrows) continue;
            #pragma unroll
            for (int j = 0; j < 8; ++j)
                xwb_out[(size_t)orow * 128 + j * 16 + c] = (ushort)bfbits(ac2[j][r]);
        }
    }

    // pool: threads 0..127, one col each; run-compress over 64 rows
    if (tid < 128) {
        int f = tid;
        int nend = nrows - rowb; if (nend > 64) nend = 64;
        int cur = sb[0];
        float acc2 = 0.f;
        for (int rl = 0; rl < nend; ++rl) {
            int bb = sb[rl];
            if (bb != cur) {
                atomicAdd(&z[(size_t)cur * 384 + zoff + f], acc2);
                acc2 = 0.f; cur = bb;
            }
            uint byte = ((uint)(rl * 256 + f * 2)) ^ ((uint)(rl & 7) << 4);
            acc2 += bf2f(*(const ushort*)((const char*)hl + byte));
        }
        atomicAdd(&z[(size_t)cur * 384 + zoff + f], acc2);
    }
}

// ------------------------------------------------------- sparse aggregation
// one wave per node; lane holds 2 feats. Tiered 16/4/1 gather unroll (MLP).
__global__ __launch_bounds__(256) void agg_kernel(
    const uint* __restrict__ xwb, const int* __restrict__ rowptr,
    const uint* __restrict__ ecv,
    const float* __restrict__ dinv, const float* __restrict__ bias,
    uint* __restrict__ outu, int coff, int n)
{
    int node = (int)((blockIdx.x * (size_t)blockDim.x + threadIdx.x) >> 6);
    int lane = threadIdx.x & 63;
    if (node >= n) return;
    float d = dinv[node];
    uint  g = xwb[(size_t)node * 64 + lane];
    float bx = 0.f, by = 0.f;
    int e0 = rowptr[node], e1 = rowptr[node + 1];
    int e = e0;
    for (; e + 16 <= e1; e += 16) {
        uint rec[16];
        #pragma unroll
        for (int q = 0; q < 16; ++q) rec[q] = ecv[e + q];
        uint gq[16];
        #pragma unroll
        for (int q = 0; q < 16; ++q)
            gq[q] = xwb[(size_t)(rec[q] & 0xffffu) * 64 + lane];
        #pragma unroll
        for (int q = 0; q < 16; ++q) {
            float v = __half2float(__ushort_as_half((ushort)(rec[q] >> 16)));
            bx = fmaf(v, bflo(gq[q]), bx);
            by = fmaf(v, bfhi(gq[q]), by);
        }
    }
    for (; e + 4 <= e1; e += 4) {
        uint rec[4];
        #pragma unroll
        for (int q = 0; q < 4; ++q) rec[q] = ecv[e + q];
        uint gq[4];
        #pragma unroll
        for (int q = 0; q < 4; ++q)
            gq[q] = xwb[(size_t)(rec[q] & 0xffffu) * 64 + lane];
        #pragma unroll
        for (int q = 0; q < 4; ++q) {
            float v = __half2float(__ushort_as_half((ushort)(rec[q] >> 16)));
            bx = fmaf(v, bflo(gq[q]), bx);
            by = fmaf(v, bfhi(gq[q]), by);
        }
    }
    for (; e < e1; ++e) {
        uint rec = ecv[e];
        uint gg = xwb[(size_t)(rec & 0xffffu) * 64 + lane];
        float v = __half2float(__ushort_as_half((ushort)(rec >> 16)));
        bx = fmaf(v, bflo(gg), bx);
        by = fmaf(v, bfhi(gg), by);
    }
    float sw = d * d;
    float ax = fmaf(d, bx, bflo(g) * sw);
    float ay = fmaf(d, by, bfhi(g) * sw);
    float2 b = *(const float2*)&bias[lane * 2];
    ax = fmaxf(ax + b.x, 0.f);
    ay = fmaxf(ay + b.y, 0.f);
    outu[(size_t)node * 128 + coff + lane] = bfbits(ax) | (bfbits(ay) << 16);
}

// ---------------------------------------------------------------- head
__global__ __launch_bounds__(128) void head_kernel(
    const float* __restrict__ z,
    const float* __restrict__ g,  const float* __restrict__ be,
    const float* __restrict__ mu, const float* __restrict__ var,
    const float* __restrict__ w1, const float* __restrict__ b1,
    const float* __restrict__ w2, const float* __restrict__ b2,
    float* __restrict__ out)
{
    int gi = blockIdx.x;
    int t  = threadIdx.x;
    __shared__ float zs[384];
    __shared__ float h1[128];
    __shared__ float lg[10];
    for (int i = t; i < 384; i += 128) {
        float v = z[(size_t)gi * 384 + i];
        v = (v - mu[i]) * rsqrtf(var[i] + 1e-5f) * g[i] + be[i];
        zs[i] = v;
    }
    __syncthreads();
    float acc = b1[t];
    for (int k = 0; k < 384; ++k) acc = fmaf(zs[k], w1[(size_t)k * 128 + t], acc);
    h1[t] = fmaxf(acc, 0.f);
    __syncthreads();
    if (t < 10) {
        float a2 = b2[t];
        for (int k = 0; k < 128; ++k) a2 = fmaf(h1[k], w2[(size_t)k * 10 + t], a2);
        lg[t] = a2;
    }
    __syncthreads();
    if (t == 0) {
        float m = lg[0];
        for (int i = 1; i < 10; ++i) m = fmaxf(m, lg[i]);
        float e[10], s = 0.f;
        for (int i = 0; i < 10; ++i) { e[i] = expf(lg[i] - m); s += e[i]; }
        float inv = 1.f / s;
        for (int i = 0; i < 10; ++i) out[(size_t)gi * 10 + i] = e[i] * inv;
    }
}

// ---------------------------------------------------------------- launch
extern "C" void kernel_launch(void* const* d_in, const int* in_sizes, int n_in,
                              void* d_out, int out_size, void* d_ws, size_t ws_size,
                              hipStream_t stream)
{
    const float* x      = (const float*)d_in[0];
    const float* ea     = (const float*)d_in[1];
    const float* conv_w = (const float*)d_in[2];
    const float* conv_b = (const float*)d_in[3];
    const float* jk_w   = (const float*)d_in[4];
    const float* jk_b   = (const float*)d_in[5];
    const float* bn_g   = (const float*)d_in[6];
    const float* bn_b   = (const float*)d_in[7];
    const float* bn_m   = (const float*)d_in[8];
    const float* bn_v   = (const float*)d_in[9];
    const float* w1     = (const float*)d_in[10];
    const float* b1     = (const float*)d_in[11];
    const float* w2     = (const float*)d_in[12];
    const float* b2     = (const float*)d_in[13];
    const int*   eidx   = (const int*)d_in[14];
    const int*   batch  = (const int*)d_in[15];
    const int* srcv = eidx;
    const int* dstv = eidx + NE;
    float* out = (float*)d_out;

    char* ws = (char*)d_ws;
    size_t off = 0;
    auto alloc = [&](size_t b) { size_t o = off; off += (b + 511) & ~(size_t)511; return o; };
    u64*   pk     = (u64*)  (ws + alloc((size_t)NN * 8));
    float* z      = (float*)(ws + alloc((size_t)NG * 384 * 4));
    uint*  ctr    = (uint*) (ws + alloc(512));
    size_t zero_bytes = off;
    float* dinv   = (float*)(ws + alloc((size_t)NN * 4));
    int*   rowptr = (int*)  (ws + alloc((size_t)(NN + 1) * 4));
    ushort* rankb = (ushort*)(ws + alloc((size_t)NE * 2));
    uint*  ecv    = (uint*) (ws + alloc((size_t)NE * 4));
    ushort* wbc   = (ushort*)(ws + alloc((size_t)6 * 128 * 128 * 2));
    ushort* wbj   = (ushort*)(ws + alloc((size_t)3 * 256 * 128 * 2));
    uint*  xwb    = (uint*) (ws + alloc((size_t)NN * 64 * 4));
    uint*  xsb    = (uint*) (ws + alloc((size_t)NN * 128 * 4));   // [NN][256] bf16
    int*   bsum   = (int*)  (ws + alloc((size_t)256 * 4));
    int*   boff   = (int*)  (ws + alloc((size_t)257 * 4));
    (void)ws_size; (void)in_sizes; (void)n_in; (void)out_size;

    hipMemsetAsync(d_ws, 0, zero_bytes, stream);

    const int NB = (NN + 255) / 256;
    prep_kernel<<<EB + WBC + WBJ, 256, 0, stream>>>(dstv, ea, pk, rankb,
                                                    conv_w, wbc, jk_w, wbj);
    scan_ab_kernel<<<NB, 256, 0, stream>>>(pk, bsum, dinv, boff, ctr, NN, NB);
    scan_final_kernel<<<NB, 256, 0, stream>>>(pk, boff, rowptr, NN, NB);
    // fill + conv0 fused (independent partitions)
    fillconv_kernel<<<EB + GB, 256, 0, stream>>>(srcv, dstv, ea, dinv, rowptr,
                                                 rankb, ecv, x, wbc,
                                                 (ushort*)xwb);

    const int AB = (NN * 64 + 255) / 256;

    for (int l = 0; l < 3; ++l) {
        agg_kernel<<<AB, 256, 0, stream>>>(
            xwb, rowptr, ecv, dinv, conv_b + (size_t)(l * 2 + 0) * 128,
            xsb, 0, NN);
        conv_gemm_kernel<<<GB, 256, 0, stream>>>(
            (const ushort*)xsb, 128, 256, wbc + (size_t)(l * 2 + 1) * 128 * 128,
            (ushort*)xwb, NN);
        agg_kernel<<<AB, 256, 0, stream>>>(
            xwb, rowptr, ecv, dinv, conv_b + (size_t)(l * 2 + 1) * 128,
            xsb, 64, NN);
        if (l < 2) {
            jk_fused_kernel<true><<<GB, 256, 0, stream>>>(
                (const ushort*)xsb, wbj + (size_t)l * 256 * 128,
                jk_b + (size_t)l * 128, batch, z, l * 128,
                wbc + (size_t)(l + 1) * 2 * 128 * 128, (ushort*)xwb, NN);
        } else {
            jk_fused_kernel<false><<<GB, 256, 0, stream>>>(
                (const ushort*)xsb, wbj + (size_t)l * 256 * 128,
                jk_b + (size_t)l * 128, batch, z, l * 128,
                nullptr, nullptr, NN);
        }
    }
    head_kernel<<<NG, 128, 0, stream>>>(z, bn_g, bn_b, bn_m, bn_v,
                                        w1, b1, w2, b2, out);
}